// Round 6
// baseline (46.555 us; speedup 1.0000x reference)
//
#include <hip/hip_runtime.h>

// QuantumVelocityField: fused 4->128->128->6 silu MLP (fp16 MFMA, fp32 accum)
// + 3-layer RY/RZ single-qubit sim. B = 262144.
//
// R6 vs R5 (VALU/occupancy-bound; LDS-per-4-wave-block capped occupancy at
// 16 waves/CU while VGPR=80 allows 24):
//  - 512-thread blocks (8 waves), grid 1024, ONE 32-row tile per wave. Weight
//    image shared by 8 waves -> 3 blocks/CU x 8 waves = 24 waves/CU.
//  - fragment-major weight images: A-fragments stored [frag][lane][8] so all
//    LDS reads are base(lane)+immediate-offset ds_read_b128 -- no address
//    VALU, no q==0/ln<6 guards, conflict-free linear pattern.
//  - __launch_bounds__(512,5): VGPR cap 102 (R5 measured 80; no spill risk).

typedef _Float16 half8 __attribute__((ext_vector_type(8)));
typedef _Float16 half4 __attribute__((ext_vector_type(4)));
typedef _Float16 half2 __attribute__((ext_vector_type(2)));
typedef float f32x4 __attribute__((ext_vector_type(4)));
typedef float f32x2 __attribute__((ext_vector_type(2)));

#define NBLOCKS 1024          // 1024 blocks * 8 waves * 32 rows = 262144
#define WS_IMG_BYTES 49152    // staged image (incl. pad), 6 * 512 * 16B

union Half8U { half8 v; half2 h2[4]; };

__device__ __forceinline__ half2 silu2(float x0, float x1) {
    float s0 = __fdividef(x0, 1.0f + __expf(-x0));
    float s1 = __fdividef(x1, 1.0f + __expf(-x1));
    return __builtin_bit_cast(half2, __builtin_amdgcn_cvt_pkrtz(s0, s1));
}
__device__ __forceinline__ unsigned int pk16(float x0, float x1) {
    return __builtin_bit_cast(unsigned int, __builtin_amdgcn_cvt_pkrtz(x0, x1));
}

#define DSFENCE() do { asm volatile("s_waitcnt lgkmcnt(0)" ::: "memory"); \
                       __builtin_amdgcn_wave_barrier(); } while (0)

// ---------------------------------------------------------------------------
// Image layout (bytes):
//   [0, 32768)      W2 frags: frag f=s*8+nt, h[f*512 + l*8 + j] =
//                   W2[s*32+(j>>2)*16+(l>>4)*4+(j&3)][nt*16+(l&15)]
//   [32768, 36864)  W1 frags (padded): h[16384 + nt*256 + l*4 + j] =
//                   (l<16) ? W1[j][nt*16+l] : 0
//   [36864, 40960)  W3 frags (padded): h[18432 + s*512 + l*8 + j] =
//                   ((l&15)<6) ? W3[s*32+(j>>2)*16+(l>>4)*4+(j&3)][l&15] : 0
//   [40960, 41472)  b1 (f32);  [41472, 41984) b2 (f32);  [41984, 49152) pad
// ---------------------------------------------------------------------------
__global__ void qvf_pack(const float* __restrict__ W1g, const float* __restrict__ b1g,
                         const float* __restrict__ W2g, const float* __restrict__ b2g,
                         const float* __restrict__ W3g, const float* __restrict__ b3g,
                         unsigned char* __restrict__ ws) {
    _Float16* h = (_Float16*)ws;
    float*    f = (float*)ws;
    const int b = blockIdx.x, tid = threadIdx.x;
    if (b < 64) {
        int i = b * 256 + tid;                  // coalesced W2 read
        int k = i >> 7, n2 = i & 127;
        float wv = W2g[i];
        int s = k >> 5, hi = (k >> 4) & 1, q = (k >> 2) & 3, c = k & 3;
        int frag = s * 8 + (n2 >> 4), l = q * 16 + (n2 & 15), j = hi * 4 + c;
        h[frag * 512 + l * 8 + j] = (_Float16)wv;
    } else {
        int i = (b - 64) * 256 + tid;           // [0, 2048) across 8 blocks
        {   // W1 padded
            int nt = i >> 8, l = (i >> 2) & 63, j = i & 3;
            h[16384 + i] = (l < 16) ? (_Float16)W1g[j * 128 + nt * 16 + l]
                                    : (_Float16)0.f;
        }
        {   // W3 padded
            int s = i >> 9, l = (i >> 3) & 63, j = i & 7;
            int q = l >> 4, ln = l & 15;
            h[18432 + i] = (ln < 6)
                ? (_Float16)W3g[(s * 32 + ((j >> 2) << 4) + q * 4 + (j & 3)) * 6 + ln]
                : (_Float16)0.f;
        }
        if (b == 64) {
            if (tid < 128)      f[10240 + tid] = b1g[tid];
            else                f[10368 + (tid - 128)] = b2g[tid - 128];
        }
        if (i < 1792) f[10496 + i] = 0.f;       // pad to 49152B
    }
}

// ---------------------------------------------------------------------------
template <bool PREPACK>
__global__ __launch_bounds__(512, 5)
void qvf_kernel(const float* __restrict__ tg, const float* __restrict__ blg,
                const float* __restrict__ W1g, const float* __restrict__ b1g,
                const float* __restrict__ W2g, const float* __restrict__ b2g,
                const float* __restrict__ W3g, const float* __restrict__ b3g,
                const unsigned char* __restrict__ ws,
                float* __restrict__ out) {
    __shared__ __align__(16) unsigned char sRaw[52224];
    const _Float16* sW2f = (const _Float16*)sRaw;                  // 32 frags
    const _Float16* sW1f = (const _Float16*)(sRaw + 32768);        // 8 frags (b64)
    const _Float16* sW3f = (const _Float16*)(sRaw + 36864);        // 4 frags
    const float*    sB1  = (const float*)(sRaw + 40960);
    const float*    sB2  = (const float*)(sRaw + 41472);

    const int tid  = threadIdx.x;
    const int w    = tid >> 6;          // 8 waves
    const int lane = tid & 63;
    const int q    = lane >> 4;
    const int ln   = lane & 15;

    unsigned int* sPU = (unsigned int*)(sRaw + 49152) + w * 96;  // 32 rows x 3 dw
    float*        sPF = (float*)sPU;

    // ---- stage the weight image ----
    if (PREPACK) {
        #pragma unroll
        for (int i = 0; i < 6; ++i) {
            int off = (i * 512 + tid) * 16;
            *(f32x4*)(sRaw + off) = *(const f32x4*)(ws + off);
        }
    } else {
        _Float16* h = (_Float16*)sRaw;
        float*    f = (float*)sRaw;
        for (int i = tid; i < 16384; i += 512) {
            int k = i >> 7, n2 = i & 127;
            float wv = W2g[i];
            int s = k >> 5, hi = (k >> 4) & 1, q2 = (k >> 2) & 3, c = k & 3;
            int frag = s * 8 + (n2 >> 4), l = q2 * 16 + (n2 & 15), j = hi * 4 + c;
            h[frag * 512 + l * 8 + j] = (_Float16)wv;
        }
        for (int i = tid; i < 2048; i += 512) {
            int nt = i >> 8, l = (i >> 2) & 63, j = i & 3;
            h[16384 + i] = (l < 16) ? (_Float16)W1g[j * 128 + nt * 16 + l]
                                    : (_Float16)0.f;
            int s = i >> 9, l2 = (i >> 3) & 63, j2 = i & 7;
            int q2 = l2 >> 4, ln2 = l2 & 15;
            h[18432 + i] = (ln2 < 6)
                ? (_Float16)W3g[(s * 32 + ((j2 >> 2) << 4) + q2 * 4 + (j2 & 3)) * 6 + ln2]
                : (_Float16)0.f;
        }
        if (tid < 128)       f[10240 + tid] = b1g[tid];
        else if (tid < 256)  f[10368 + (tid - 128)] = b2g[tid - 128];
    }
    // b3 per-lane regs
    float b3c[4];
    #pragma unroll
    for (int r = 0; r < 4; ++r) {
        int n3 = 4 * q + r;
        b3c[r] = (n3 < 6) ? b3g[n3] : 0.0f;
    }

    // ---- this wave's 32 rows; input loads (q==0 lanes) ----
    const int rowb = blockIdx.x * 256 + w * 32;
    half8 bf1[2] = {{}, {}};
    if (q == 0) {
        #pragma unroll
        for (int mt = 0; mt < 2; ++mt) {
            int m = rowb + mt * 16 + ln;
            bf1[mt][0] = (_Float16)tg[m];
            bf1[mt][1] = (_Float16)blg[3 * m + 0];
            bf1[mt][2] = (_Float16)blg[3 * m + 1];
            bf1[mt][3] = (_Float16)blg[3 * m + 2];
        }
    }

    __syncthreads();

    // ---- layer 1: C-init = b1 frag; A = ungated b64 frag reads ----
    f32x4 acc1[2][8];
    #pragma unroll
    for (int nt = 0; nt < 8; ++nt) {
        half4 lo = *(const half4*)&sW1f[nt * 256 + lane * 4];
        half8 a1 = {lo[0], lo[1], lo[2], lo[3],
                    (_Float16)0.f, (_Float16)0.f, (_Float16)0.f, (_Float16)0.f};
        f32x4 bb = *(const f32x4*)&sB1[nt * 16 + 4 * q];
        acc1[0][nt] = __builtin_amdgcn_mfma_f32_16x16x32_f16(a1, bf1[0], bb, 0, 0, 0);
        acc1[1][nt] = __builtin_amdgcn_mfma_f32_16x16x32_f16(a1, bf1[1], bb, 0, 0, 0);
    }

    // ---- epilogue 1: silu -> layer-2 B frags ----
    half8 bf2[2][4];
    #pragma unroll
    for (int mt = 0; mt < 2; ++mt) {
        #pragma unroll
        for (int s = 0; s < 4; ++s) {
            Half8U u;
            #pragma unroll
            for (int hj = 0; hj < 2; ++hj) {
                int nt = 2 * s + hj;
                u.h2[hj * 2 + 0] = silu2(acc1[mt][nt][0], acc1[mt][nt][1]);
                u.h2[hj * 2 + 1] = silu2(acc1[mt][nt][2], acc1[mt][nt][3]);
            }
            bf2[mt][s] = u.v;
        }
    }

    // ---- layer 2: C-init = b2 at s==0; A = immediate-offset b128 reads ----
    f32x4 acc2[2][8];
    #pragma unroll
    for (int s = 0; s < 4; ++s) {
        #pragma unroll
        for (int nt = 0; nt < 8; ++nt) {
            half8 a2 = *(const half8*)&sW2f[(s * 8 + nt) * 512 + lane * 8];
            if (s == 0) {
                f32x4 bb = *(const f32x4*)&sB2[nt * 16 + 4 * q];
                acc2[0][nt] = __builtin_amdgcn_mfma_f32_16x16x32_f16(a2, bf2[0][0], bb, 0, 0, 0);
                acc2[1][nt] = __builtin_amdgcn_mfma_f32_16x16x32_f16(a2, bf2[1][0], bb, 0, 0, 0);
            } else {
                acc2[0][nt] = __builtin_amdgcn_mfma_f32_16x16x32_f16(a2, bf2[0][s], acc2[0][nt], 0, 0, 0);
                acc2[1][nt] = __builtin_amdgcn_mfma_f32_16x16x32_f16(a2, bf2[1][s], acc2[1][nt], 0, 0, 0);
            }
        }
    }

    // ---- epilogue 2: silu -> layer-3 B frags ----
    half8 bf3[2][4];
    #pragma unroll
    for (int mt = 0; mt < 2; ++mt) {
        #pragma unroll
        for (int s = 0; s < 4; ++s) {
            Half8U u;
            #pragma unroll
            for (int hj = 0; hj < 2; ++hj) {
                int nt = 2 * s + hj;
                u.h2[hj * 2 + 0] = silu2(acc2[mt][nt][0], acc2[mt][nt][1]);
                u.h2[hj * 2 + 1] = silu2(acc2[mt][nt][2], acc2[mt][nt][3]);
            }
            bf3[mt][s] = u.v;
        }
    }

    // ---- layer 3: C-init = b3 regs; A = ungated b128 frag reads ----
    f32x4 acc3[2];
    acc3[0] = (f32x4){b3c[0], b3c[1], b3c[2], b3c[3]};
    acc3[1] = (f32x4){b3c[0], b3c[1], b3c[2], b3c[3]};
    #pragma unroll
    for (int s = 0; s < 4; ++s) {
        half8 a3 = *(const half8*)&sW3f[s * 512 + lane * 8];
        acc3[0] = __builtin_amdgcn_mfma_f32_16x16x32_f16(a3, bf3[0][s], acc3[0], 0, 0, 0);
        acc3[1] = __builtin_amdgcn_mfma_f32_16x16x32_f16(a3, bf3[1][s], acc3[1], 0, 0, 0);
    }

    // ---- epilogue 3: pack params fp16 -> wave strip ----
    #pragma unroll
    for (int mt = 0; mt < 2; ++mt) {
        int row = mt * 16 + ln;
        if (q == 0) {
            sPU[row * 3 + 0] = pk16(acc3[mt][0], acc3[mt][1]);  // th1, ph1
            sPU[row * 3 + 1] = pk16(acc3[mt][2], acc3[mt][3]);  // th2, ph2
        } else if (q == 1) {
            sPU[row * 3 + 2] = pk16(acc3[mt][0], acc3[mt][1]);  // th3, ph3
        }
    }
    DSFENCE();   // wave-private: params visible to all lanes

    // ---- circuit sim: lanes 0..31, one row each ----
    if (lane < 32) {
        half2 h0 = __builtin_bit_cast(half2, sPU[lane * 3 + 0]);
        half2 h1 = __builtin_bit_cast(half2, sPU[lane * 3 + 1]);
        half2 h2 = __builtin_bit_cast(half2, sPU[lane * 3 + 2]);
        float pr[6] = {(float)h0[0], (float)h0[1], (float)h1[0],
                       (float)h1[1], (float)h2[0], (float)h2[1]};
        float ar = 1.f, ai = 0.f, br = 0.f, bi = 0.f;
        #pragma unroll
        for (int l = 0; l < 3; ++l) {
            float th = pr[2 * l] * 0.5f;
            float ph = pr[2 * l + 1] * 0.5f;
            float s1, c1, se, ce;
            __sincosf(th, &s1, &c1);
            float a1r = c1 * ar - s1 * br, a1i = c1 * ai - s1 * bi;
            float b1r = s1 * ar + c1 * br, b1i = s1 * ai + c1 * bi;
            __sincosf(ph, &se, &ce);
            ar = ce * a1r + se * a1i; ai = ce * a1i - se * a1r;
            br = ce * b1r - se * b1i; bi = ce * b1i + se * b1r;
        }
        // same-lane same-address: ordered within a lane
        sPF[lane * 3 + 0] = 2.f * (ar * br + ai * bi);
        sPF[lane * 3 + 1] = 2.f * (ar * bi - ai * br);
        sPF[lane * 3 + 2] = ar * ar + ai * ai - br * br - bi * bi;
    }
    DSFENCE();   // results visible cross-lane

    // ---- coalesced stores: 96 floats per wave, 48-lane dwordx2 ----
    if (lane < 48) {
        f32x2 vv = *(const f32x2*)&sPF[2 * lane];
        *(f32x2*)&out[3 * rowb + 2 * lane] = vv;
    }
}

extern "C" void kernel_launch(void* const* d_in, const int* in_sizes, int n_in,
                              void* d_out, int out_size, void* d_ws, size_t ws_size,
                              hipStream_t stream) {
    const float* t  = (const float*)d_in[0];
    const float* bl = (const float*)d_in[1];
    const float* W1 = (const float*)d_in[2];
    const float* b1 = (const float*)d_in[3];
    const float* W2 = (const float*)d_in[4];
    const float* b2 = (const float*)d_in[5];
    const float* W3 = (const float*)d_in[6];
    const float* b3 = (const float*)d_in[7];
    float* out = (float*)d_out;

    if (ws_size >= WS_IMG_BYTES) {
        unsigned char* ws = (unsigned char*)d_ws;
        qvf_pack<<<72, 256, 0, stream>>>(W1, b1, W2, b2, W3, b3, ws);
        qvf_kernel<true><<<NBLOCKS, 512, 0, stream>>>(t, bl, W1, b1, W2, b2, W3, b3, ws, out);
    } else {
        qvf_kernel<false><<<NBLOCKS, 512, 0, stream>>>(t, bl, W1, b1, W2, b2, W3, b3, nullptr, out);
    }
}

// Round 7
// 45.462 us; speedup vs baseline: 1.0240x; 1.0240x over previous
//
#include <hip/hip_runtime.h>

// QuantumVelocityField: fused 4->128->128->6 silu MLP (fp16 MFMA, fp32 accum)
// + 3-layer RY/RZ single-qubit sim. B = 262144.
//
// R7 = R5 (best: 43.4us, no spill) + R6's fragment-major W2 image:
//  - W2 stored [frag][lane][8]: layer-2 A-reads are lane-linear b128 with
//    immediate offsets -- zero bank conflicts (R6-verified), no XOR/addr VALU.
//  - 256-thread blocks, __launch_bounds__(256,3): arch-VGPR budget stays
//    ~168 so accumulator-AGPR split doesn't starve arch VGPRs (R3/R6 spill
//    mechanism). LDS 39936B -> 4 blocks/CU.
//  - bias folded into MFMA C-operand; deferred full-wave 64-row circuit.

typedef _Float16 half8 __attribute__((ext_vector_type(8)));
typedef _Float16 half4 __attribute__((ext_vector_type(4)));
typedef _Float16 half2 __attribute__((ext_vector_type(2)));
typedef float f32x4 __attribute__((ext_vector_type(4)));
typedef float f32x2 __attribute__((ext_vector_type(2)));

#define NBLOCKS 1024          // 1024 blocks * 4 waves * 2 tiles * 32 rows = 262144
#define WS_IMG_BYTES 36864    // 9 * 256 threads * 16B

union Half8U { half8 v; half2 h2[4]; };

__device__ __forceinline__ half2 silu2(float x0, float x1) {
    float s0 = __fdividef(x0, 1.0f + __expf(-x0));
    float s1 = __fdividef(x1, 1.0f + __expf(-x1));
    return __builtin_bit_cast(half2, __builtin_amdgcn_cvt_pkrtz(s0, s1));
}
__device__ __forceinline__ unsigned int pk16(float x0, float x1) {
    return __builtin_bit_cast(unsigned int, __builtin_amdgcn_cvt_pkrtz(x0, x1));
}

#define DSFENCE() do { asm volatile("s_waitcnt lgkmcnt(0)" ::: "memory"); \
                       __builtin_amdgcn_wave_barrier(); } while (0)

// ---------------------------------------------------------------------------
// Image layout (half index h[], float index f[]):
//   h[0,16384)      W2 frags: f=s*8+nt: h[f*512 + l*8 + j] =
//                   W2[s*32+(j>>2)*16+(l>>4)*4+(j&3)][nt*16+(l&15)]
//   h[16384,16896)  W1 compact: h[16384 + nt*64 + ln*4 + j] = W1[j][nt*16+ln]
//   h[16896,17664)  W3 compact: h[16896 + ((s*6+ln)*4+q)*8 + j] =
//                   W3[(s*32+(j>>2)*16+q*4+(j&3))*6 + ln]
//   f[8832,8960)    b1;  f[8960,9088) b2;  pad to f[9216) = 36864B
// ---------------------------------------------------------------------------
__global__ void qvf_pack(const float* __restrict__ W1g, const float* __restrict__ b1g,
                         const float* __restrict__ W2g, const float* __restrict__ b2g,
                         const float* __restrict__ W3g, const float* __restrict__ b3g,
                         unsigned char* __restrict__ ws) {
    _Float16* h = (_Float16*)ws;
    float*    f = (float*)ws;
    const int b = blockIdx.x, tid = threadIdx.x;
    if (b < 64) {
        int i = b * 256 + tid;                  // coalesced W2 read
        int k = i >> 7, n2 = i & 127;
        float wv = W2g[i];
        int s = k >> 5, hi = (k >> 4) & 1, qv = (k >> 2) & 3, c = k & 3;
        int frag = s * 8 + (n2 >> 4), l = qv * 16 + (n2 & 15), j = hi * 4 + c;
        h[frag * 512 + l * 8 + j] = (_Float16)wv;
    } else {
        for (int i = tid; i < 512; i += 256) {          // W1 compact
            int j = i & 3, ln = (i >> 2) & 15, nt = i >> 6;
            h[16384 + i] = (_Float16)W1g[j * 128 + nt * 16 + ln];
        }
        for (int i = tid; i < 768; i += 256) {          // W3 compact
            int j = i & 7, t2 = i >> 3;
            int q = t2 & 3, u = t2 >> 2;
            int ln = u % 6, s = u / 6;
            int k = s * 32 + ((j >> 2) << 4) + q * 4 + (j & 3);
            h[16896 + i] = (_Float16)W3g[k * 6 + ln];
        }
        if (tid < 128) { f[8832 + tid] = b1g[tid]; f[8960 + tid] = b2g[tid]; }
        for (int i = 9088 + tid; i < 9216; i += 256) f[i] = 0.f;
    }
}

// ---------------------------------------------------------------------------
template <bool PREPACK>
__global__ __launch_bounds__(256, 3)
void qvf_kernel(const float* __restrict__ tg, const float* __restrict__ blg,
                const float* __restrict__ W1g, const float* __restrict__ b1g,
                const float* __restrict__ W2g, const float* __restrict__ b2g,
                const float* __restrict__ W3g, const float* __restrict__ b3g,
                const unsigned char* __restrict__ ws,
                float* __restrict__ out) {
    __shared__ __align__(16) unsigned char sRaw[39936];
    const _Float16* sW2f = (const _Float16*)sRaw;              // 32 frags x 1KB
    const _Float16* sW1  = (const _Float16*)(sRaw + 32768);    // compact
    const _Float16* sW3  = (const _Float16*)(sRaw + 33792);    // compact
    const float*    sB1  = (const float*)(sRaw + 35328);
    const float*    sB2  = (const float*)(sRaw + 35840);

    const int tid  = threadIdx.x;
    const int w    = tid >> 6;
    const int lane = tid & 63;
    const int q    = lane >> 4;
    const int ln   = lane & 15;

    unsigned int* sPU = (unsigned int*)(sRaw + 36864) + w * 192;  // 64 rows x 3 dw
    float*        sPF = (float*)sPU;

    // ---- stage the weight image ----
    if (PREPACK) {
        #pragma unroll
        for (int i = 0; i < 9; ++i) {
            int off = (i * 256 + tid) * 16;
            *(f32x4*)(sRaw + off) = *(const f32x4*)(ws + off);
        }
    } else {
        _Float16* h = (_Float16*)sRaw;
        float*    f = (float*)sRaw;
        for (int i = tid; i < 16384; i += 256) {
            int k = i >> 7, n2 = i & 127;
            float wv = W2g[i];
            int s = k >> 5, hi = (k >> 4) & 1, qv = (k >> 2) & 3, c = k & 3;
            int frag = s * 8 + (n2 >> 4), l = qv * 16 + (n2 & 15), j = hi * 4 + c;
            h[frag * 512 + l * 8 + j] = (_Float16)wv;
        }
        for (int i = tid; i < 512; i += 256) {
            int j = i & 3, l2 = (i >> 2) & 15, nt = i >> 6;
            h[16384 + i] = (_Float16)W1g[j * 128 + nt * 16 + l2];
        }
        for (int i = tid; i < 768; i += 256) {
            int j = i & 7, t2 = i >> 3;
            int q2 = t2 & 3, u = t2 >> 2;
            int l2 = u % 6, s = u / 6;
            int k = s * 32 + ((j >> 2) << 4) + q2 * 4 + (j & 3);
            h[16896 + i] = (_Float16)W3g[k * 6 + l2];
        }
        if (tid < 128) { f[8832 + tid] = b1g[tid]; f[8960 + tid] = b2g[tid]; }
    }
    // b3 per-lane regs
    float b3c[4];
    #pragma unroll
    for (int r = 0; r < 4; ++r) {
        int n3 = 4 * q + r;
        b3c[r] = (n3 < 6) ? b3g[n3] : 0.0f;
    }

    // ---- prefetch both tiles' inputs (q==0 lanes) ----
    const int base0 = blockIdx.x * 256 + w * 32;   // tile0 rows; tile1 = +128
    half8 bf1[2][2] = {{{}, {}}, {{}, {}}};
    if (q == 0) {
        #pragma unroll
        for (int t2 = 0; t2 < 2; ++t2) {
            #pragma unroll
            for (int mt = 0; mt < 2; ++mt) {
                int m = base0 + t2 * 128 + mt * 16 + ln;
                bf1[t2][mt][0] = (_Float16)tg[m];
                bf1[t2][mt][1] = (_Float16)blg[3 * m + 0];
                bf1[t2][mt][2] = (_Float16)blg[3 * m + 1];
                bf1[t2][mt][3] = (_Float16)blg[3 * m + 2];
            }
        }
    }

    __syncthreads();

    #pragma unroll
    for (int tt = 0; tt < 2; ++tt) {
        // ---- layer 1: C-init = b1 frag ----
        f32x4 acc1[2][8];
        #pragma unroll
        for (int nt = 0; nt < 8; ++nt) {
            half8 a1 = {};
            if (q == 0) {
                half4 lo = *(const half4*)&sW1[nt * 64 + ln * 4];
                a1[0] = lo[0]; a1[1] = lo[1]; a1[2] = lo[2]; a1[3] = lo[3];
            }
            f32x4 bb = *(const f32x4*)&sB1[nt * 16 + 4 * q];
            acc1[0][nt] = __builtin_amdgcn_mfma_f32_16x16x32_f16(a1, bf1[tt][0], bb, 0, 0, 0);
            acc1[1][nt] = __builtin_amdgcn_mfma_f32_16x16x32_f16(a1, bf1[tt][1], bb, 0, 0, 0);
        }

        // ---- epilogue 1: silu only ----
        half8 bf2[2][4];
        #pragma unroll
        for (int mt = 0; mt < 2; ++mt) {
            #pragma unroll
            for (int s = 0; s < 4; ++s) {
                Half8U u;
                #pragma unroll
                for (int hj = 0; hj < 2; ++hj) {
                    int nt = 2 * s + hj;
                    u.h2[hj * 2 + 0] = silu2(acc1[mt][nt][0], acc1[mt][nt][1]);
                    u.h2[hj * 2 + 1] = silu2(acc1[mt][nt][2], acc1[mt][nt][3]);
                }
                bf2[mt][s] = u.v;
            }
        }

        // ---- layer 2: fragment-major A (lane-linear b128, conflict-free) ----
        f32x4 acc2[2][8];
        #pragma unroll
        for (int s = 0; s < 4; ++s) {
            #pragma unroll
            for (int nt = 0; nt < 8; ++nt) {
                half8 a2 = *(const half8*)&sW2f[(s * 8 + nt) * 512 + lane * 8];
                if (s == 0) {
                    f32x4 bb = *(const f32x4*)&sB2[nt * 16 + 4 * q];
                    acc2[0][nt] = __builtin_amdgcn_mfma_f32_16x16x32_f16(a2, bf2[0][0], bb, 0, 0, 0);
                    acc2[1][nt] = __builtin_amdgcn_mfma_f32_16x16x32_f16(a2, bf2[1][0], bb, 0, 0, 0);
                } else {
                    acc2[0][nt] = __builtin_amdgcn_mfma_f32_16x16x32_f16(a2, bf2[0][s], acc2[0][nt], 0, 0, 0);
                    acc2[1][nt] = __builtin_amdgcn_mfma_f32_16x16x32_f16(a2, bf2[1][s], acc2[1][nt], 0, 0, 0);
                }
            }
        }

        // ---- epilogue 2: silu only ----
        half8 bf3[2][4];
        #pragma unroll
        for (int mt = 0; mt < 2; ++mt) {
            #pragma unroll
            for (int s = 0; s < 4; ++s) {
                Half8U u;
                #pragma unroll
                for (int hj = 0; hj < 2; ++hj) {
                    int nt = 2 * s + hj;
                    u.h2[hj * 2 + 0] = silu2(acc2[mt][nt][0], acc2[mt][nt][1]);
                    u.h2[hj * 2 + 1] = silu2(acc2[mt][nt][2], acc2[mt][nt][3]);
                }
                bf3[mt][s] = u.v;
            }
        }

        // ---- layer 3: C-init = b3 regs ----
        f32x4 acc3[2];
        acc3[0] = (f32x4){b3c[0], b3c[1], b3c[2], b3c[3]};
        acc3[1] = (f32x4){b3c[0], b3c[1], b3c[2], b3c[3]};
        #pragma unroll
        for (int s = 0; s < 4; ++s) {
            half8 a3 = {};
            if (ln < 6) a3 = *(const half8*)&sW3[((s * 6 + ln) * 4 + q) * 8];
            acc3[0] = __builtin_amdgcn_mfma_f32_16x16x32_f16(a3, bf3[0][s], acc3[0], 0, 0, 0);
            acc3[1] = __builtin_amdgcn_mfma_f32_16x16x32_f16(a3, bf3[1][s], acc3[1], 0, 0, 0);
        }

        // ---- epilogue 3: pack params fp16 -> LDS (stride-3 dwords) ----
        #pragma unroll
        for (int mt = 0; mt < 2; ++mt) {
            int row = tt * 32 + mt * 16 + ln;
            if (q == 0) {
                sPU[row * 3 + 0] = pk16(acc3[mt][0], acc3[mt][1]);  // th1, ph1
                sPU[row * 3 + 1] = pk16(acc3[mt][2], acc3[mt][3]);  // th2, ph2
            } else if (q == 1) {
                sPU[row * 3 + 2] = pk16(acc3[mt][0], acc3[mt][1]);  // th3, ph3
            }
        }
    }
    DSFENCE();   // wave-private: params visible to all lanes

    // ---- circuit sim: 64 rows across 64 lanes ----
    {
        half2 h0 = __builtin_bit_cast(half2, sPU[lane * 3 + 0]);
        half2 h1 = __builtin_bit_cast(half2, sPU[lane * 3 + 1]);
        half2 h2 = __builtin_bit_cast(half2, sPU[lane * 3 + 2]);
        float pr[6] = {(float)h0[0], (float)h0[1], (float)h1[0],
                       (float)h1[1], (float)h2[0], (float)h2[1]};
        float ar = 1.f, ai = 0.f, br = 0.f, bi = 0.f;
        #pragma unroll
        for (int l = 0; l < 3; ++l) {
            float th = pr[2 * l] * 0.5f;
            float ph = pr[2 * l + 1] * 0.5f;
            float s1, c1, se, ce;
            __sincosf(th, &s1, &c1);
            float a1r = c1 * ar - s1 * br, a1i = c1 * ai - s1 * bi;
            float b1r = s1 * ar + c1 * br, b1i = s1 * ai + c1 * bi;
            __sincosf(ph, &se, &ce);
            ar = ce * a1r + se * a1i; ai = ce * a1i - se * a1r;
            br = ce * b1r - se * b1i; bi = ce * b1i + se * b1r;
        }
        // same-lane same-address: ordered within a lane
        sPF[lane * 3 + 0] = 2.f * (ar * br + ai * bi);
        sPF[lane * 3 + 1] = 2.f * (ar * bi - ai * br);
        sPF[lane * 3 + 2] = ar * ar + ai * ai - br * br - bi * bi;
    }
    DSFENCE();   // outputs visible cross-lane

    // ---- coalesced stores: 96 floats per tile-half, 48-lane dwordx2 ----
    if (lane < 48) {
        f32x2 v0 = *(const f32x2*)&sPF[2 * lane];
        *(f32x2*)&out[3 * base0 + 2 * lane] = v0;                  // tile 0
        f32x2 v1 = *(const f32x2*)&sPF[96 + 2 * lane];
        *(f32x2*)&out[3 * (base0 + 128) + 2 * lane] = v1;          // tile 1
    }
}

extern "C" void kernel_launch(void* const* d_in, const int* in_sizes, int n_in,
                              void* d_out, int out_size, void* d_ws, size_t ws_size,
                              hipStream_t stream) {
    const float* t  = (const float*)d_in[0];
    const float* bl = (const float*)d_in[1];
    const float* W1 = (const float*)d_in[2];
    const float* b1 = (const float*)d_in[3];
    const float* W2 = (const float*)d_in[4];
    const float* b2 = (const float*)d_in[5];
    const float* W3 = (const float*)d_in[6];
    const float* b3 = (const float*)d_in[7];
    float* out = (float*)d_out;

    if (ws_size >= WS_IMG_BYTES) {
        unsigned char* ws = (unsigned char*)d_ws;
        qvf_pack<<<65, 256, 0, stream>>>(W1, b1, W2, b2, W3, b3, ws);
        qvf_kernel<true><<<NBLOCKS, 256, 0, stream>>>(t, bl, W1, b1, W2, b2, W3, b3, ws, out);
    } else {
        qvf_kernel<false><<<NBLOCKS, 256, 0, stream>>>(t, bl, W1, b1, W2, b2, W3, b3, nullptr, out);
    }
}